// Round 5
// baseline (2467.782 us; speedup 1.0000x reference)
//
#include <hip/hip_runtime.h>

// ---------------------------------------------------------------------------
// GCN3D: 3x GCNConv + fc (global), instance-norm, cluster pool, 2x GCNConv
// (pooled 1024-cluster graph), gather-broadcast, 3x GCNConv + fc (out).
// N=100000 nodes, E=1600000 edges, C=1024 clusters. All f32.
// R2: dense fc layers -> LDS-tiled register-blocked SGEMM (k_gemm).
// R3: atomic cluster pooling -> cluster-CSR gather reduction (k_poolavg).
// R4: k_gemm rework: BK=16 (LDS 41.5KB->20.7KB, occupancy 18%->~50%),
//     8x8 register tile for BN=256, __launch_bounds__(256,4), BM=64.
// ---------------------------------------------------------------------------

#define NCLUST 1024

__device__ __forceinline__ float elu1(float x) { return x > 0.f ? x : expm1f(x); }

__global__ void k_zero(int4* __restrict__ p, int n4) {
    int i = blockIdx.x * 256 + threadIdx.x;
    if (i < n4) p[i] = make_int4(0, 0, 0, 0);
}

// ---------------- CSR build (shared by edge graph and cluster lists) --------
__global__ void k_hist(const int* __restrict__ key, int* __restrict__ deg, int E) {
    int e = blockIdx.x * 256 + threadIdx.x;
    if (e < E) atomicAdd(&deg[key[e]], 1);
}

__global__ void k_scan_block(const int* __restrict__ deg, int* __restrict__ rowptr,
                             int* __restrict__ bsum, int n) {
    __shared__ int lds[256];
    int tid = threadIdx.x;
    int base = blockIdx.x * 1024 + tid * 4;
    int v0 = base + 0 < n ? deg[base + 0] : 0;
    int v1 = base + 1 < n ? deg[base + 1] : 0;
    int v2 = base + 2 < n ? deg[base + 2] : 0;
    int v3 = base + 3 < n ? deg[base + 3] : 0;
    int tsum = v0 + v1 + v2 + v3;
    lds[tid] = tsum; __syncthreads();
    for (int off = 1; off < 256; off <<= 1) {
        int t = (tid >= off) ? lds[tid - off] : 0;
        __syncthreads();
        lds[tid] += t;
        __syncthreads();
    }
    int run = lds[tid] - tsum;
    if (base + 0 < n) rowptr[base + 0] = run; run += v0;
    if (base + 1 < n) rowptr[base + 1] = run; run += v1;
    if (base + 2 < n) rowptr[base + 2] = run; run += v2;
    if (base + 3 < n) rowptr[base + 3] = run;
    if (tid == 255) bsum[blockIdx.x] = lds[255];
}

__global__ void k_scan_tops(int* __restrict__ bsum, int nb) {
    __shared__ int lds[128];
    int tid = threadIdx.x;
    int v = tid < nb ? bsum[tid] : 0;
    lds[tid] = v; __syncthreads();
    for (int off = 1; off < 128; off <<= 1) {
        int t = (tid >= off) ? lds[tid - off] : 0;
        __syncthreads();
        lds[tid] += t;
        __syncthreads();
    }
    if (tid < nb) bsum[tid] = lds[tid] - v;
}

__global__ void k_scan_add(int* __restrict__ rowptr, const int* __restrict__ bsum, int n) {
    int i = blockIdx.x * 256 + threadIdx.x;
    if (i < n) rowptr[i] += bsum[i >> 10];
}

__global__ void k_dinv_bc(const int* __restrict__ deg, const int* __restrict__ cluster,
                          const int* __restrict__ inb, float* __restrict__ dinv,
                          int* __restrict__ bc, int n) {
    int i = blockIdx.x * 256 + threadIdx.x;
    if (i < n) {
        dinv[i] = rsqrtf((float)deg[i] + 1.0f);
        bc[i] = cluster[i] + inb[i] * NCLUST;
    }
}

__global__ void k_fill(const int* __restrict__ src, const int* __restrict__ dst,
                       const float* __restrict__ dinv, const int* __restrict__ rowptr,
                       int* __restrict__ fill, int* __restrict__ csr_src,
                       float* __restrict__ csr_w, int E) {
    int e = blockIdx.x * 256 + threadIdx.x;
    if (e >= E) return;
    int d = dst[e];
    int pos = rowptr[d] + atomicAdd(&fill[d], 1);
    int s = src[e];
    csr_src[pos] = s;
    csr_w[pos] = dinv[s];
}

// cluster member lists
__global__ void k_cfill(const int* __restrict__ bc, const int* __restrict__ crowptr,
                        int* __restrict__ cfill, int* __restrict__ cnodes, int n) {
    int i = blockIdx.x * 256 + threadIdx.x;
    if (i >= n) return;
    int c = bc[i];
    int pos = crowptr[c] + atomicAdd(&cfill[c], 1);
    cnodes[pos] = i;
}

// ---------------- GCN propagation: out = S*h (+bias, elu) ----------------
__global__ __launch_bounds__(256) void k_prop4(
        const float* __restrict__ h, const float* __restrict__ dinv,
        const int* __restrict__ rowptr, const int* __restrict__ deg,
        const int* __restrict__ csr_src, const float* __restrict__ csr_w,
        const float* __restrict__ bias, float* __restrict__ out,
        int n, int F, int lshift, int flags) {
    int gid = blockIdx.x * 256 + threadIdx.x;
    int node = gid >> lshift;
    if (node >= n) return;
    int fi = (gid & ((1 << lshift) - 1)) * 4;
    int start = rowptr[node];
    int cnt = deg[node];
    float ax = 0.f, ay = 0.f, az = 0.f, aw = 0.f;
    for (int j = 0; j < cnt; j++) {
        int s = csr_src[start + j];
        float w = csr_w[start + j];
        const float4 v = *reinterpret_cast<const float4*>(&h[(size_t)s * F + fi]);
        ax += w * v.x; ay += w * v.y; az += w * v.z; aw += w * v.w;
    }
    float di = dinv[node];
    const float4 sv = *reinterpret_cast<const float4*>(&h[(size_t)node * F + fi]);
    float4 o;
    o.x = di * ax + di * di * sv.x;
    o.y = di * ay + di * di * sv.y;
    o.z = di * az + di * di * sv.z;
    o.w = di * aw + di * di * sv.w;
    if (flags) {
        const float4 b = *reinterpret_cast<const float4*>(&bias[fi]);
        o.x = elu1(o.x + b.x); o.y = elu1(o.y + b.y);
        o.z = elu1(o.z + b.z); o.w = elu1(o.w + b.w);
    }
    *reinterpret_cast<float4*>(&out[(size_t)node * F + fi]) = o;
}

__global__ void k_prop3(const float* __restrict__ h, const float* __restrict__ dinv,
                        const int* __restrict__ rowptr, const int* __restrict__ deg,
                        const int* __restrict__ csr_src, const float* __restrict__ csr_w,
                        const float* __restrict__ bias, float* __restrict__ out,
                        int n, int flags) {
    int node = blockIdx.x * 256 + threadIdx.x;
    if (node >= n) return;
    int start = rowptr[node], cnt = deg[node];
    float a0 = 0.f, a1 = 0.f, a2 = 0.f;
    for (int j = 0; j < cnt; j++) {
        int s = csr_src[start + j];
        float w = csr_w[start + j];
        a0 += w * h[(size_t)s * 3 + 0];
        a1 += w * h[(size_t)s * 3 + 1];
        a2 += w * h[(size_t)s * 3 + 2];
    }
    float di = dinv[node];
    float o0 = di * a0 + di * di * h[(size_t)node * 3 + 0];
    float o1 = di * a1 + di * di * h[(size_t)node * 3 + 1];
    float o2 = di * a2 + di * di * h[(size_t)node * 3 + 2];
    if (flags) {
        o0 = elu1(o0 + bias[0]); o1 = elu1(o1 + bias[1]); o2 = elu1(o2 + bias[2]);
    }
    out[(size_t)node * 3 + 0] = o0;
    out[(size_t)node * 3 + 1] = o1;
    out[(size_t)node * 3 + 2] = o2;
}

// ---------------- tiled SGEMM: C = A[N,K] @ W[K,BN] (+add[idx], +bias, elu) --
// 256 threads, BM=64 rows/block, BN = full M (in-place safe: block-local rows,
// stores after final barrier). BK=16. REP row-replication: LG=64/REP lanes per
// group own TN=BN/LG cols (chunks of 4 at col, col+BN/2). K % 16 == 0.
template <int BM, int BN, int BK, int REP>
__global__ __launch_bounds__(256, 4) void k_gemm(
        const float* __restrict__ A, const float* __restrict__ W,
        const float* __restrict__ bias, const float* __restrict__ add,
        const int* __restrict__ addidx, float* __restrict__ C,
        int N, int K, int flags) {
    constexpr int LG = 64 / REP;          // lanes per rep-group
    constexpr int TN = BN / LG;           // cols per lane (4 or 8)
    constexpr int TM = BM / (4 * REP);    // rows per thread (2/4/8)
    constexpr int NCH = TN / 4;           // 1 or 2 col chunks
    constexpr int LDA = BM + 4;
    __shared__ float As[BK * LDA];        // transposed [k][row]
    __shared__ float Ws[BK * BN];         // [k][col]
    const int t = threadIdx.x;
    const int w = t >> 6, l = t & 63;
    const int lg = l % LG;
    const int g = w * REP + l / LG;       // row-group 0..4*REP-1
    const int col = lg * 4;
    const int row0 = blockIdx.x * BM;

    float acc[TM][TN];
#pragma unroll
    for (int i = 0; i < TM; i++)
#pragma unroll
        for (int j = 0; j < TN; j++) acc[i][j] = 0.f;

    const int nk = K / BK;
    for (int s = 0; s < nk; ++s) {
        // stage A tile transposed: BM*BK = 1024 floats = 1 float4/thread
        {
            int f = t * 4;
            int r = f / BK;
            int kk = f % BK;
            int grow = row0 + r; grow = grow < N ? grow : N - 1;
            const float4 v = *reinterpret_cast<const float4*>(&A[(size_t)grow * K + s * BK + kk]);
            As[(kk + 0) * LDA + r] = v.x;
            As[(kk + 1) * LDA + r] = v.y;
            As[(kk + 2) * LDA + r] = v.z;
            As[(kk + 3) * LDA + r] = v.w;
        }
        // stage W tile linear
        {
            constexpr int NW4 = (BK * BN) / 4;
#pragma unroll
            for (int f4 = t; f4 < NW4; f4 += 256) {
                int f = f4 * 4;
                int kk = f / BN;
                int m = f % BN;
                *reinterpret_cast<float4*>(&Ws[kk * BN + m]) =
                    *reinterpret_cast<const float4*>(&W[(size_t)(s * BK + kk) * BN + m]);
            }
        }
        __syncthreads();
#pragma unroll
        for (int k = 0; k < BK; ++k) {
            float av[TM];
            if constexpr (TM >= 4) {
#pragma unroll
                for (int i = 0; i < TM; i += 4) {
                    const float4 v = *reinterpret_cast<const float4*>(&As[k * LDA + g * TM + i]);
                    av[i] = v.x; av[i + 1] = v.y; av[i + 2] = v.z; av[i + 3] = v.w;
                }
            } else {
                const float2 v = *reinterpret_cast<const float2*>(&As[k * LDA + g * TM]);
                av[0] = v.x; av[1] = v.y;
            }
            float wv[TN];
#pragma unroll
            for (int c = 0; c < NCH; ++c) {
                const float4 v = *reinterpret_cast<const float4*>(&Ws[k * BN + col + c * (BN / 2)]);
                wv[c * 4 + 0] = v.x; wv[c * 4 + 1] = v.y;
                wv[c * 4 + 2] = v.z; wv[c * 4 + 3] = v.w;
            }
#pragma unroll
            for (int i = 0; i < TM; i++)
#pragma unroll
                for (int j = 0; j < TN; j++) acc[i][j] += av[i] * wv[j];
        }
        __syncthreads();
    }
    // epilogue
#pragma unroll
    for (int i = 0; i < TM; i++) {
        int row = row0 + g * TM + i;
        if (row >= N) continue;
        int g2 = (add != nullptr) ? addidx[row] : 0;
#pragma unroll
        for (int c = 0; c < NCH; ++c) {
            int cc = col + c * (BN / 2);
            float o[4];
#pragma unroll
            for (int j = 0; j < 4; j++) o[j] = acc[i][c * 4 + j];
            if (add != nullptr) {
                const float4 v = *reinterpret_cast<const float4*>(&add[(size_t)g2 * BN + cc]);
                o[0] += v.x; o[1] += v.y; o[2] += v.z; o[3] += v.w;
            }
            if (flags) {
                const float4 b = *reinterpret_cast<const float4*>(&bias[cc]);
                o[0] = elu1(o[0] + b.x); o[1] = elu1(o[1] + b.y);
                o[2] = elu1(o[2] + b.z); o[3] = elu1(o[3] + b.w);
            }
            *reinterpret_cast<float4*>(&C[(size_t)row * BN + cc]) =
                make_float4(o[0], o[1], o[2], o[3]);
        }
    }
}

// ---------------- simple fc (small shapes: K=3 layer, local C=1024 stack) ----
template <int M, int RPT>
__global__ __launch_bounds__(256) void k_fc(
        const float* __restrict__ A, const float* __restrict__ W,
        const float* __restrict__ bias, const float* __restrict__ add,
        const int* __restrict__ addidx, float* __restrict__ C,
        int N, int K, int flags) {
    constexpr int TX = M / 4;
    constexpr int TY = 256 / TX;
    constexpr int RB = TY * RPT;
    int tx = threadIdx.x % TX;
    int ty = threadIdx.x / TX;
    int row0 = blockIdx.x * RB + ty * RPT;
    float4 acc[RPT];
#pragma unroll
    for (int r = 0; r < RPT; r++) acc[r] = make_float4(0.f, 0.f, 0.f, 0.f);
    for (int k = 0; k < K; k++) {
        float4 w = *reinterpret_cast<const float4*>(&W[(size_t)k * M + tx * 4]);
#pragma unroll
        for (int r = 0; r < RPT; r++) {
            int row = row0 + r;
            row = row < N ? row : N - 1;
            float a = A[(size_t)row * K + k];
            acc[r].x += a * w.x; acc[r].y += a * w.y;
            acc[r].z += a * w.z; acc[r].w += a * w.w;
        }
    }
    if (add != nullptr) {
#pragma unroll
        for (int r = 0; r < RPT; r++) {
            int row = row0 + r;
            if (row < N) {
                int g = addidx[row];
                const float4 v = *reinterpret_cast<const float4*>(&add[(size_t)g * M + tx * 4]);
                acc[r].x += v.x; acc[r].y += v.y; acc[r].z += v.z; acc[r].w += v.w;
            }
        }
    }
    __syncthreads();
    float4 b = make_float4(0.f, 0.f, 0.f, 0.f);
    if (flags) b = *reinterpret_cast<const float4*>(&bias[tx * 4]);
#pragma unroll
    for (int r = 0; r < RPT; r++) {
        int row = row0 + r;
        if (row >= N) break;
        float4 o = acc[r];
        o.x += b.x; o.y += b.y; o.z += b.z; o.w += b.w;
        if (flags) { o.x = elu1(o.x); o.y = elu1(o.y); o.z = elu1(o.z); o.w = elu1(o.w); }
        *reinterpret_cast<float4*>(&C[(size_t)row * M + tx * 4]) = o;
    }
}

// M = 3 (W: K x 3)
__global__ void k_fc3(const float* __restrict__ A, const float* __restrict__ W,
                      const float* __restrict__ b, float* __restrict__ C,
                      int n, int K, int flags) {
    int r = blockIdx.x * 256 + threadIdx.x;
    if (r >= n) return;
    float a0 = 0.f, a1 = 0.f, a2 = 0.f;
    for (int k = 0; k < K; k++) {
        float a = A[(size_t)r * K + k];
        a0 += a * W[k * 3 + 0]; a1 += a * W[k * 3 + 1]; a2 += a * W[k * 3 + 2];
    }
    if (flags) {
        a0 = elu1(a0 + b[0]); a1 = elu1(a1 + b[1]); a2 = elu1(a2 + b[2]);
    }
    C[(size_t)r * 3 + 0] = a0;
    C[(size_t)r * 3 + 1] = a1;
    C[(size_t)r * 3 + 2] = a2;
}

// ---------------- instance norm (in-place apply) ----------------
__global__ void k_instats(const float* __restrict__ h, float* __restrict__ sum,
                          float* __restrict__ sumsq, int n) {
    int c = threadIdx.x;
    int r0 = blockIdx.x * 128;
    int r1 = r0 + 128 < n ? r0 + 128 : n;
    float s = 0.f, q = 0.f;
    for (int r = r0; r < r1; r++) {
        float v = h[(size_t)r * 256 + c];
        s += v; q += v * v;
    }
    atomicAdd(&sum[c], s);
    atomicAdd(&sumsq[c], q);
}

__global__ void k_infinal(const float* __restrict__ sum, const float* __restrict__ sumsq,
                          float* __restrict__ mu, float* __restrict__ rstd, int n) {
    int c = threadIdx.x;
    float m = sum[c] / (float)n;
    float var = sumsq[c] / (float)n - m * m;
    mu[c] = m;
    rstd[c] = rsqrtf(var + 1e-5f);
}

__global__ void k_innorm(float* __restrict__ h, const float* __restrict__ mu,
                         const float* __restrict__ rstd, int n) {
    int gid = blockIdx.x * 256 + threadIdx.x;
    int node = gid >> 6;
    if (node >= n) return;
    int c = (gid & 63) * 4;
    float4 v = *reinterpret_cast<const float4*>(&h[(size_t)node * 256 + c]);
    float4 m = *reinterpret_cast<const float4*>(&mu[c]);
    float4 rs = *reinterpret_cast<const float4*>(&rstd[c]);
    v.x = (v.x - m.x) * rs.x; v.y = (v.y - m.y) * rs.y;
    v.z = (v.z - m.z) * rs.z; v.w = (v.w - m.w) * rs.w;
    *reinterpret_cast<float4*>(&h[(size_t)node * 256 + c]) = v;
}

// ---------------- cluster pooling (CSR gather, no atomics) ----------------
__global__ __launch_bounds__(256) void k_poolavg(
        const float* __restrict__ y, const int* __restrict__ crowptr,
        const int* __restrict__ cdeg, const int* __restrict__ cnodes,
        float* __restrict__ px) {
    int cl = blockIdx.x;
    int c  = threadIdx.x;
    int start = crowptr[cl];
    int cnt = cdeg[cl];
    float acc = 0.f;
    for (int j = 0; j < cnt; j++) {
        int node = cnodes[start + j];
        acc += y[(size_t)node * 256 + c];
    }
    px[(size_t)cl * 256 + c] = acc / fmaxf((float)cnt, 1.0f);
}

__global__ void k_pooledges(const int* __restrict__ src, const int* __restrict__ dst,
                            const int* __restrict__ bc, unsigned char* __restrict__ bmT, int E) {
    int e = blockIdx.x * 256 + threadIdx.x;
    if (e >= E) return;
    int ps = bc[src[e]];
    int pd = bc[dst[e]];
    bmT[(size_t)pd * NCLUST + ps] = 1;
}

__global__ void k_pooldeg(const unsigned char* __restrict__ bmT, float* __restrict__ dinvp) {
    int d = blockIdx.x * 256 + threadIdx.x;
    if (d >= NCLUST) return;
    int cnt = 0;
    for (int s = 0; s < NCLUST; s++) cnt += (s != d) ? (int)bmT[(size_t)d * NCLUST + s] : 0;
    dinvp[d] = rsqrtf((float)cnt + 1.0f);
}

__global__ void k_proppool(const float* __restrict__ h, const float* __restrict__ dinvp,
                           const unsigned char* __restrict__ bmT, const float* __restrict__ bias,
                           float* __restrict__ out, int F) {
    int d = blockIdx.x;
    int f = threadIdx.x;
    float acc = 0.f;
    for (int s = 0; s < NCLUST; s++) {
        if (s == d) continue;
        if (bmT[(size_t)d * NCLUST + s]) acc += dinvp[s] * h[(size_t)s * F + f];
    }
    float di = dinvp[d];
    float r = di * acc + di * di * h[(size_t)d * F + f] + bias[f];
    out[(size_t)d * F + f] = elu1(r);
}

// ---------------------------------------------------------------------------
extern "C" void kernel_launch(void* const* d_in, const int* in_sizes, int n_in,
                              void* d_out, int out_size, void* d_ws, size_t ws_size,
                              hipStream_t stream) {
    const float* x       = (const float*)d_in[0];
    const int*   adj     = (const int*)d_in[1];
    const int*   inb     = (const int*)d_in[3];
    const int*   cluster = (const int*)d_in[4];
    const float* WG1  = (const float*)d_in[5];   const float* bG1  = (const float*)d_in[6];
    const float* WfG1 = (const float*)d_in[7];   const float* bfG1 = (const float*)d_in[8];
    const float* WG2  = (const float*)d_in[9];   const float* bG2  = (const float*)d_in[10];
    const float* WfG2 = (const float*)d_in[11];  const float* bfG2 = (const float*)d_in[12];
    const float* WL1  = (const float*)d_in[13];  const float* bL1  = (const float*)d_in[14];
    const float* WfL1 = (const float*)d_in[15];  const float* bfL1 = (const float*)d_in[16];
    const float* WL2  = (const float*)d_in[17];  const float* bL2  = (const float*)d_in[18];
    const float* WfL2 = (const float*)d_in[19];  const float* bfL2 = (const float*)d_in[20];
    const float* WO1  = (const float*)d_in[21];  const float* bO1  = (const float*)d_in[22];
    const float* WfO1 = (const float*)d_in[23];  const float* bfO1 = (const float*)d_in[24];
    const float* WO2  = (const float*)d_in[25];  const float* bO2  = (const float*)d_in[26];
    const float* WfO2 = (const float*)d_in[27];  const float* bfO2 = (const float*)d_in[28];
    const float* WO3  = (const float*)d_in[29];  const float* bO3  = (const float*)d_in[30];
    const float* WfO3 = (const float*)d_in[31];  const float* bfO3 = (const float*)d_in[32];
    float* out = (float*)d_out;

    const int n = in_sizes[0] / 3;       // 100000
    const int E = in_sizes[1] / 2;       // 1600000
    const int* src = adj;
    const int* dst = adj + E;

    // ---- workspace carve (~173 MB) ----
    char* ws = (char*)d_ws;
    size_t off = 0;
    auto alloc = [&](size_t bytes) -> void* {
        void* p = ws + off;
        off = (off + bytes + 255) & ~(size_t)255;
        return p;
    };
    int*   deg     = (int*)alloc((size_t)n * 4);     // zero span 1 start
    int*   fill    = (int*)alloc((size_t)n * 4);
    int*   cdeg    = (int*)alloc(NCLUST * 4);
    int*   cfill   = (int*)alloc(NCLUST * 4);
    int*   rowptr  = (int*)alloc((size_t)n * 4);     // zero span 1 end (exclusive)
    int*   crowptr = (int*)alloc(NCLUST * 4);
    int*   cnodes  = (int*)alloc((size_t)n * 4);
    int*   bcarr   = (int*)alloc((size_t)n * 4);
    float* dinv    = (float*)alloc((size_t)n * 4);
    int*   bsum    = (int*)alloc(512);
    int*   csr_src = (int*)alloc((size_t)E * 4);
    float* csr_w   = (float*)alloc((size_t)E * 4);
    float* X       = (float*)alloc((size_t)n * 256 * 4);
    float* B       = (float*)alloc((size_t)n * 128 * 4);
    float* insum   = (float*)alloc(256 * 4);         // zero span 2 start
    float* insumsq = (float*)alloc(256 * 4);
    float* px      = (float*)alloc((size_t)NCLUST * 256 * 4);
    unsigned char* bmT = (unsigned char*)alloc((size_t)NCLUST * NCLUST);
    float* mu      = (float*)alloc(256 * 4);         // zero span 2 end (exclusive)
    float* rstd    = (float*)alloc(256 * 4);
    float* dinvp   = (float*)alloc(NCLUST * 4);
    float* lA      = (float*)alloc((size_t)NCLUST * 128 * 4);
    float* lB      = (float*)alloc((size_t)NCLUST * 128 * 4);
    (void)ws_size; (void)n_in; (void)out_size;

    float* B0 = B;
    float* B1 = B + (size_t)n * 64;

    auto cdiv = [](int a, int b) { return (a + b - 1) / b; };
    const int EB = cdiv(E, 256);

    // ---- zero scratch ----
    int nz1 = (int)(((char*)rowptr - (char*)deg) / 16);
    int nz2 = (int)(((char*)mu - (char*)insum) / 16);
    k_zero<<<cdiv(nz1, 256), 256, 0, stream>>>((int4*)deg, nz1);
    k_zero<<<cdiv(nz2, 256), 256, 0, stream>>>((int4*)insum, nz2);

    // ---- CSR build (edges) ----
    k_hist<<<EB, 256, 0, stream>>>(dst, deg, E);
    int nb = cdiv(n, 1024);
    k_scan_block<<<nb, 256, 0, stream>>>(deg, rowptr, bsum, n);
    k_scan_tops<<<1, 128, 0, stream>>>(bsum, nb);
    k_scan_add<<<cdiv(n, 256), 256, 0, stream>>>(rowptr, bsum, n);
    k_dinv_bc<<<cdiv(n, 256), 256, 0, stream>>>(deg, cluster, inb, dinv, bcarr, n);
    k_fill<<<EB, 256, 0, stream>>>(src, dst, dinv, rowptr, fill, csr_src, csr_w, E);

    // ---- CSR build (cluster member lists) ----
    k_hist<<<cdiv(n, 256), 256, 0, stream>>>(bcarr, cdeg, n);
    k_scan_block<<<1, 256, 0, stream>>>(cdeg, crowptr, bsum, NCLUST);
    k_cfill<<<cdiv(n, 256), 256, 0, stream>>>(bcarr, crowptr, cfill, cnodes, n);

    // ---- global GCN stack ----
    k_prop3<<<cdiv(n, 256), 256, 0, stream>>>(x, dinv, rowptr, deg, csr_src, csr_w,
                                              nullptr, B0, n, 0);
    k_fc<64, 2><<<cdiv(n, 32), 256, 0, stream>>>(B0, WG1, bG1, nullptr, nullptr, B1, n, 3, 1);
    // h2 = elu(h1 @ WfG1 + bfG1)  (B1 in-place, 64 square)
    k_gemm<64, 64, 16, 4><<<cdiv(n, 64), 256, 0, stream>>>(B1, WfG1, bfG1, nullptr, nullptr,
                                                           B1, n, 64, 1);
    k_prop4<<<cdiv(n * 16, 256), 256, 0, stream>>>(B1, dinv, rowptr, deg, csr_src, csr_w,
                                                   nullptr, B0, n, 64, 4, 0);
    // h3 = elu(p64 @ WG2 + bG2)  (X)
    k_gemm<64, 256, 16, 2><<<cdiv(n, 64), 256, 0, stream>>>(B0, WG2, bG2, nullptr, nullptr,
                                                            X, n, 64, 1);
    // h4 = elu(h3 @ WfG2 + bfG2)  (X in-place)
    k_gemm<64, 256, 16, 2><<<cdiv(n, 64), 256, 0, stream>>>(X, WfG2, bfG2, nullptr, nullptr,
                                                            X, n, 256, 1);

    // ---- instance norm (in place) -> y = X ----
    k_instats<<<cdiv(n, 128), 256, 0, stream>>>(X, insum, insumsq, n);
    k_infinal<<<1, 256, 0, stream>>>(insum, insumsq, mu, rstd, n);
    k_innorm<<<cdiv(n * 64, 256), 256, 0, stream>>>(X, mu, rstd, n);

    // ---- cluster pooling (gather) ----
    k_poolavg<<<NCLUST, 256, 0, stream>>>(X, crowptr, cdeg, cnodes, px);
    k_pooledges<<<EB, 256, 0, stream>>>(src, dst, bcarr, bmT, E);
    k_pooldeg<<<4, 256, 0, stream>>>(bmT, dinvp);

    // ---- local (pooled) GCN stack ----
    k_fc<128, 2><<<cdiv(NCLUST, 16), 256, 0, stream>>>(px, WL1, nullptr, nullptr, nullptr,
                                                       lA, NCLUST, 256, 0);
    k_proppool<<<NCLUST, 128, 0, stream>>>(lA, dinvp, bmT, bL1, lB, 128);
    k_fc<128, 2><<<cdiv(NCLUST, 16), 256, 0, stream>>>(lB, WfL1, bfL1, nullptr, nullptr,
                                                       lA, NCLUST, 128, 1);
    k_fc<64, 2><<<cdiv(NCLUST, 32), 256, 0, stream>>>(lA, WL2, nullptr, nullptr, nullptr,
                                                      lB, NCLUST, 128, 0);
    k_proppool<<<NCLUST, 64, 0, stream>>>(lB, dinvp, bmT, bL2, lA, 64);
    k_fc<64, 2><<<cdiv(NCLUST, 32), 256, 0, stream>>>(lA, WfL2, bfL2, nullptr, nullptr,
                                                      lB, NCLUST, 64, 1);
    k_fc<128, 2><<<cdiv(NCLUST, 16), 256, 0, stream>>>(lB, WO1 + (size_t)256 * 128, nullptr,
                                                       nullptr, nullptr, lA, NCLUST, 64, 0);

    // ---- output GCN stack ----
    // t1 = y @ WO1[0:256,:] + compO[bc]  (B, N x 128)
    k_gemm<64, 128, 16, 2><<<cdiv(n, 64), 256, 0, stream>>>(X, WO1, nullptr, lA, bcarr,
                                                            B, n, 256, 0);
    k_prop4<<<cdiv(n * 32, 256), 256, 0, stream>>>(B, dinv, rowptr, deg, csr_src, csr_w,
                                                   bO1, X, n, 128, 5, 1);
    // o2 = elu(o1 @ WfO1 + bfO1)  (X in-place)
    k_gemm<64, 128, 16, 2><<<cdiv(n, 64), 256, 0, stream>>>(X, WfO1, bfO1, nullptr, nullptr,
                                                            X, n, 128, 1);
    // t2 = o2 @ WO2  (B, N x 32)
    k_gemm<64, 32, 16, 8><<<cdiv(n, 64), 256, 0, stream>>>(X, WO2, nullptr, nullptr, nullptr,
                                                           B, n, 128, 0);
    k_prop4<<<cdiv(n * 8, 256), 256, 0, stream>>>(B, dinv, rowptr, deg, csr_src, csr_w,
                                                  bO2, X, n, 32, 3, 1);
    // o4 = elu(o3 @ WfO2 + bfO2)  (X in-place)
    k_gemm<64, 32, 16, 8><<<cdiv(n, 64), 256, 0, stream>>>(X, WfO2, bfO2, nullptr, nullptr,
                                                           X, n, 32, 1);
    k_fc3<<<cdiv(n, 256), 256, 0, stream>>>(X, WO3, nullptr, B, n, 32, 0);
    k_prop3<<<cdiv(n, 256), 256, 0, stream>>>(B, dinv, rowptr, deg, csr_src, csr_w,
                                              bO3, X, n, 1);
    k_fc3<<<cdiv(n, 256), 256, 0, stream>>>(X, WfO3, bfO3, out, n, 3, 1);
}

// Round 6
// 1726.551 us; speedup vs baseline: 1.4293x; 1.4293x over previous
//
#include <hip/hip_runtime.h>

// ---------------------------------------------------------------------------
// GCN3D: 3x GCNConv + fc (global), instance-norm, cluster pool, 2x GCNConv
// (pooled 1024-cluster graph), gather-broadcast, 3x GCNConv + fc (out).
// N=100000 nodes, E=1600000 edges, C=1024 clusters. All f32.
// R2: dense fc layers -> LDS-tiled register-blocked SGEMM (k_gemm).
// R3: atomic cluster pooling -> cluster-CSR gather reduction (k_poolavg).
// R4: k_gemm BK=16, 8x8 register tile, BM=64.
// R5 FAILED: __launch_bounds__(256,4) capped VGPR at 64 -> acc tile spilled
//   to scratch (1.86GB WRITE_SIZE). R6: plain launch_bounds(256) (no min-wave
//   clause -> no forced spill); parallel k_pooldeg.
// ---------------------------------------------------------------------------

#define NCLUST 1024

__device__ __forceinline__ float elu1(float x) { return x > 0.f ? x : expm1f(x); }

__global__ void k_zero(int4* __restrict__ p, int n4) {
    int i = blockIdx.x * 256 + threadIdx.x;
    if (i < n4) p[i] = make_int4(0, 0, 0, 0);
}

// ---------------- CSR build (shared by edge graph and cluster lists) --------
__global__ void k_hist(const int* __restrict__ key, int* __restrict__ deg, int E) {
    int e = blockIdx.x * 256 + threadIdx.x;
    if (e < E) atomicAdd(&deg[key[e]], 1);
}

__global__ void k_scan_block(const int* __restrict__ deg, int* __restrict__ rowptr,
                             int* __restrict__ bsum, int n) {
    __shared__ int lds[256];
    int tid = threadIdx.x;
    int base = blockIdx.x * 1024 + tid * 4;
    int v0 = base + 0 < n ? deg[base + 0] : 0;
    int v1 = base + 1 < n ? deg[base + 1] : 0;
    int v2 = base + 2 < n ? deg[base + 2] : 0;
    int v3 = base + 3 < n ? deg[base + 3] : 0;
    int tsum = v0 + v1 + v2 + v3;
    lds[tid] = tsum; __syncthreads();
    for (int off = 1; off < 256; off <<= 1) {
        int t = (tid >= off) ? lds[tid - off] : 0;
        __syncthreads();
        lds[tid] += t;
        __syncthreads();
    }
    int run = lds[tid] - tsum;
    if (base + 0 < n) rowptr[base + 0] = run; run += v0;
    if (base + 1 < n) rowptr[base + 1] = run; run += v1;
    if (base + 2 < n) rowptr[base + 2] = run; run += v2;
    if (base + 3 < n) rowptr[base + 3] = run;
    if (tid == 255) bsum[blockIdx.x] = lds[255];
}

__global__ void k_scan_tops(int* __restrict__ bsum, int nb) {
    __shared__ int lds[128];
    int tid = threadIdx.x;
    int v = tid < nb ? bsum[tid] : 0;
    lds[tid] = v; __syncthreads();
    for (int off = 1; off < 128; off <<= 1) {
        int t = (tid >= off) ? lds[tid - off] : 0;
        __syncthreads();
        lds[tid] += t;
        __syncthreads();
    }
    if (tid < nb) bsum[tid] = lds[tid] - v;
}

__global__ void k_scan_add(int* __restrict__ rowptr, const int* __restrict__ bsum, int n) {
    int i = blockIdx.x * 256 + threadIdx.x;
    if (i < n) rowptr[i] += bsum[i >> 10];
}

__global__ void k_dinv_bc(const int* __restrict__ deg, const int* __restrict__ cluster,
                          const int* __restrict__ inb, float* __restrict__ dinv,
                          int* __restrict__ bc, int n) {
    int i = blockIdx.x * 256 + threadIdx.x;
    if (i < n) {
        dinv[i] = rsqrtf((float)deg[i] + 1.0f);
        bc[i] = cluster[i] + inb[i] * NCLUST;
    }
}

__global__ void k_fill(const int* __restrict__ src, const int* __restrict__ dst,
                       const float* __restrict__ dinv, const int* __restrict__ rowptr,
                       int* __restrict__ fill, int* __restrict__ csr_src,
                       float* __restrict__ csr_w, int E) {
    int e = blockIdx.x * 256 + threadIdx.x;
    if (e >= E) return;
    int d = dst[e];
    int pos = rowptr[d] + atomicAdd(&fill[d], 1);
    int s = src[e];
    csr_src[pos] = s;
    csr_w[pos] = dinv[s];
}

// cluster member lists
__global__ void k_cfill(const int* __restrict__ bc, const int* __restrict__ crowptr,
                        int* __restrict__ cfill, int* __restrict__ cnodes, int n) {
    int i = blockIdx.x * 256 + threadIdx.x;
    if (i >= n) return;
    int c = bc[i];
    int pos = crowptr[c] + atomicAdd(&cfill[c], 1);
    cnodes[pos] = i;
}

// ---------------- GCN propagation: out = S*h (+bias, elu) ----------------
__global__ __launch_bounds__(256) void k_prop4(
        const float* __restrict__ h, const float* __restrict__ dinv,
        const int* __restrict__ rowptr, const int* __restrict__ deg,
        const int* __restrict__ csr_src, const float* __restrict__ csr_w,
        const float* __restrict__ bias, float* __restrict__ out,
        int n, int F, int lshift, int flags) {
    int gid = blockIdx.x * 256 + threadIdx.x;
    int node = gid >> lshift;
    if (node >= n) return;
    int fi = (gid & ((1 << lshift) - 1)) * 4;
    int start = rowptr[node];
    int cnt = deg[node];
    float ax = 0.f, ay = 0.f, az = 0.f, aw = 0.f;
    for (int j = 0; j < cnt; j++) {
        int s = csr_src[start + j];
        float w = csr_w[start + j];
        const float4 v = *reinterpret_cast<const float4*>(&h[(size_t)s * F + fi]);
        ax += w * v.x; ay += w * v.y; az += w * v.z; aw += w * v.w;
    }
    float di = dinv[node];
    const float4 sv = *reinterpret_cast<const float4*>(&h[(size_t)node * F + fi]);
    float4 o;
    o.x = di * ax + di * di * sv.x;
    o.y = di * ay + di * di * sv.y;
    o.z = di * az + di * di * sv.z;
    o.w = di * aw + di * di * sv.w;
    if (flags) {
        const float4 b = *reinterpret_cast<const float4*>(&bias[fi]);
        o.x = elu1(o.x + b.x); o.y = elu1(o.y + b.y);
        o.z = elu1(o.z + b.z); o.w = elu1(o.w + b.w);
    }
    *reinterpret_cast<float4*>(&out[(size_t)node * F + fi]) = o;
}

__global__ void k_prop3(const float* __restrict__ h, const float* __restrict__ dinv,
                        const int* __restrict__ rowptr, const int* __restrict__ deg,
                        const int* __restrict__ csr_src, const float* __restrict__ csr_w,
                        const float* __restrict__ bias, float* __restrict__ out,
                        int n, int flags) {
    int node = blockIdx.x * 256 + threadIdx.x;
    if (node >= n) return;
    int start = rowptr[node], cnt = deg[node];
    float a0 = 0.f, a1 = 0.f, a2 = 0.f;
    for (int j = 0; j < cnt; j++) {
        int s = csr_src[start + j];
        float w = csr_w[start + j];
        a0 += w * h[(size_t)s * 3 + 0];
        a1 += w * h[(size_t)s * 3 + 1];
        a2 += w * h[(size_t)s * 3 + 2];
    }
    float di = dinv[node];
    float o0 = di * a0 + di * di * h[(size_t)node * 3 + 0];
    float o1 = di * a1 + di * di * h[(size_t)node * 3 + 1];
    float o2 = di * a2 + di * di * h[(size_t)node * 3 + 2];
    if (flags) {
        o0 = elu1(o0 + bias[0]); o1 = elu1(o1 + bias[1]); o2 = elu1(o2 + bias[2]);
    }
    out[(size_t)node * 3 + 0] = o0;
    out[(size_t)node * 3 + 1] = o1;
    out[(size_t)node * 3 + 2] = o2;
}

// ---------------- tiled SGEMM: C = A[N,K] @ W[K,BN] (+add[idx], +bias, elu) --
// 256 threads, BM rows/block, BN = full M (in-place safe: block-local rows,
// stores after final barrier). BK=16. REP row-replication: LG=64/REP lanes per
// group own TN=BN/LG cols (chunks of 4 at col, col+BN/2). K % 16 == 0.
// NOTE: no min-waves clause in launch_bounds -- R5 showed (256,4) caps VGPR at
// 64 and spills the accumulator tile to scratch (1.86GB of scratch writes).
template <int BM, int BN, int BK, int REP>
__global__ __launch_bounds__(256) void k_gemm(
        const float* __restrict__ A, const float* __restrict__ W,
        const float* __restrict__ bias, const float* __restrict__ add,
        const int* __restrict__ addidx, float* __restrict__ C,
        int N, int K, int flags) {
    constexpr int LG = 64 / REP;          // lanes per rep-group
    constexpr int TN = BN / LG;           // cols per lane (4 or 8)
    constexpr int TM = BM / (4 * REP);    // rows per thread (2/4/8)
    constexpr int NCH = TN / 4;           // 1 or 2 col chunks
    constexpr int LDA = BM + 4;
    __shared__ float As[BK * LDA];        // transposed [k][row]
    __shared__ float Ws[BK * BN];         // [k][col]
    const int t = threadIdx.x;
    const int w = t >> 6, l = t & 63;
    const int lg = l % LG;
    const int g = w * REP + l / LG;       // row-group 0..4*REP-1
    const int col = lg * 4;
    const int row0 = blockIdx.x * BM;

    float acc[TM][TN];
#pragma unroll
    for (int i = 0; i < TM; i++)
#pragma unroll
        for (int j = 0; j < TN; j++) acc[i][j] = 0.f;

    const int nk = K / BK;
    for (int s = 0; s < nk; ++s) {
        // stage A tile transposed: BM*BK = 1024 floats = 1 float4/thread
        {
            int f = t * 4;
            int r = f / BK;
            int kk = f % BK;
            int grow = row0 + r; grow = grow < N ? grow : N - 1;
            const float4 v = *reinterpret_cast<const float4*>(&A[(size_t)grow * K + s * BK + kk]);
            As[(kk + 0) * LDA + r] = v.x;
            As[(kk + 1) * LDA + r] = v.y;
            As[(kk + 2) * LDA + r] = v.z;
            As[(kk + 3) * LDA + r] = v.w;
        }
        // stage W tile linear
        {
            constexpr int NW4 = (BK * BN) / 4;
#pragma unroll
            for (int f4 = t; f4 < NW4; f4 += 256) {
                int f = f4 * 4;
                int kk = f / BN;
                int m = f % BN;
                *reinterpret_cast<float4*>(&Ws[kk * BN + m]) =
                    *reinterpret_cast<const float4*>(&W[(size_t)(s * BK + kk) * BN + m]);
            }
        }
        __syncthreads();
#pragma unroll
        for (int k = 0; k < BK; ++k) {
            float av[TM];
            if constexpr (TM >= 4) {
#pragma unroll
                for (int i = 0; i < TM; i += 4) {
                    const float4 v = *reinterpret_cast<const float4*>(&As[k * LDA + g * TM + i]);
                    av[i] = v.x; av[i + 1] = v.y; av[i + 2] = v.z; av[i + 3] = v.w;
                }
            } else {
                const float2 v = *reinterpret_cast<const float2*>(&As[k * LDA + g * TM]);
                av[0] = v.x; av[1] = v.y;
            }
            float wv[TN];
#pragma unroll
            for (int c = 0; c < NCH; ++c) {
                const float4 v = *reinterpret_cast<const float4*>(&Ws[k * BN + col + c * (BN / 2)]);
                wv[c * 4 + 0] = v.x; wv[c * 4 + 1] = v.y;
                wv[c * 4 + 2] = v.z; wv[c * 4 + 3] = v.w;
            }
#pragma unroll
            for (int i = 0; i < TM; i++)
#pragma unroll
                for (int j = 0; j < TN; j++) acc[i][j] += av[i] * wv[j];
        }
        __syncthreads();
    }
    // epilogue
#pragma unroll
    for (int i = 0; i < TM; i++) {
        int row = row0 + g * TM + i;
        if (row >= N) continue;
        int g2 = (add != nullptr) ? addidx[row] : 0;
#pragma unroll
        for (int c = 0; c < NCH; ++c) {
            int cc = col + c * (BN / 2);
            float o[4];
#pragma unroll
            for (int j = 0; j < 4; j++) o[j] = acc[i][c * 4 + j];
            if (add != nullptr) {
                const float4 v = *reinterpret_cast<const float4*>(&add[(size_t)g2 * BN + cc]);
                o[0] += v.x; o[1] += v.y; o[2] += v.z; o[3] += v.w;
            }
            if (flags) {
                const float4 b = *reinterpret_cast<const float4*>(&bias[cc]);
                o[0] = elu1(o[0] + b.x); o[1] = elu1(o[1] + b.y);
                o[2] = elu1(o[2] + b.z); o[3] = elu1(o[3] + b.w);
            }
            *reinterpret_cast<float4*>(&C[(size_t)row * BN + cc]) =
                make_float4(o[0], o[1], o[2], o[3]);
        }
    }
}

// ---------------- simple fc (small shapes: K=3 layer, local C=1024 stack) ----
template <int M, int RPT>
__global__ __launch_bounds__(256) void k_fc(
        const float* __restrict__ A, const float* __restrict__ W,
        const float* __restrict__ bias, const float* __restrict__ add,
        const int* __restrict__ addidx, float* __restrict__ C,
        int N, int K, int flags) {
    constexpr int TX = M / 4;
    constexpr int TY = 256 / TX;
    constexpr int RB = TY * RPT;
    int tx = threadIdx.x % TX;
    int ty = threadIdx.x / TX;
    int row0 = blockIdx.x * RB + ty * RPT;
    float4 acc[RPT];
#pragma unroll
    for (int r = 0; r < RPT; r++) acc[r] = make_float4(0.f, 0.f, 0.f, 0.f);
    for (int k = 0; k < K; k++) {
        float4 w = *reinterpret_cast<const float4*>(&W[(size_t)k * M + tx * 4]);
#pragma unroll
        for (int r = 0; r < RPT; r++) {
            int row = row0 + r;
            row = row < N ? row : N - 1;
            float a = A[(size_t)row * K + k];
            acc[r].x += a * w.x; acc[r].y += a * w.y;
            acc[r].z += a * w.z; acc[r].w += a * w.w;
        }
    }
    if (add != nullptr) {
#pragma unroll
        for (int r = 0; r < RPT; r++) {
            int row = row0 + r;
            if (row < N) {
                int g = addidx[row];
                const float4 v = *reinterpret_cast<const float4*>(&add[(size_t)g * M + tx * 4]);
                acc[r].x += v.x; acc[r].y += v.y; acc[r].z += v.z; acc[r].w += v.w;
            }
        }
    }
    __syncthreads();
    float4 b = make_float4(0.f, 0.f, 0.f, 0.f);
    if (flags) b = *reinterpret_cast<const float4*>(&bias[tx * 4]);
#pragma unroll
    for (int r = 0; r < RPT; r++) {
        int row = row0 + r;
        if (row >= N) break;
        float4 o = acc[r];
        o.x += b.x; o.y += b.y; o.z += b.z; o.w += b.w;
        if (flags) { o.x = elu1(o.x); o.y = elu1(o.y); o.z = elu1(o.z); o.w = elu1(o.w); }
        *reinterpret_cast<float4*>(&C[(size_t)row * M + tx * 4]) = o;
    }
}

// M = 3 (W: K x 3)
__global__ void k_fc3(const float* __restrict__ A, const float* __restrict__ W,
                      const float* __restrict__ b, float* __restrict__ C,
                      int n, int K, int flags) {
    int r = blockIdx.x * 256 + threadIdx.x;
    if (r >= n) return;
    float a0 = 0.f, a1 = 0.f, a2 = 0.f;
    for (int k = 0; k < K; k++) {
        float a = A[(size_t)r * K + k];
        a0 += a * W[k * 3 + 0]; a1 += a * W[k * 3 + 1]; a2 += a * W[k * 3 + 2];
    }
    if (flags) {
        a0 = elu1(a0 + b[0]); a1 = elu1(a1 + b[1]); a2 = elu1(a2 + b[2]);
    }
    C[(size_t)r * 3 + 0] = a0;
    C[(size_t)r * 3 + 1] = a1;
    C[(size_t)r * 3 + 2] = a2;
}

// ---------------- instance norm (in-place apply) ----------------
__global__ void k_instats(const float* __restrict__ h, float* __restrict__ sum,
                          float* __restrict__ sumsq, int n) {
    int c = threadIdx.x;
    int r0 = blockIdx.x * 128;
    int r1 = r0 + 128 < n ? r0 + 128 : n;
    float s = 0.f, q = 0.f;
    for (int r = r0; r < r1; r++) {
        float v = h[(size_t)r * 256 + c];
        s += v; q += v * v;
    }
    atomicAdd(&sum[c], s);
    atomicAdd(&sumsq[c], q);
}

__global__ void k_infinal(const float* __restrict__ sum, const float* __restrict__ sumsq,
                          float* __restrict__ mu, float* __restrict__ rstd, int n) {
    int c = threadIdx.x;
    float m = sum[c] / (float)n;
    float var = sumsq[c] / (float)n - m * m;
    mu[c] = m;
    rstd[c] = rsqrtf(var + 1e-5f);
}

__global__ void k_innorm(float* __restrict__ h, const float* __restrict__ mu,
                         const float* __restrict__ rstd, int n) {
    int gid = blockIdx.x * 256 + threadIdx.x;
    int node = gid >> 6;
    if (node >= n) return;
    int c = (gid & 63) * 4;
    float4 v = *reinterpret_cast<const float4*>(&h[(size_t)node * 256 + c]);
    float4 m = *reinterpret_cast<const float4*>(&mu[c]);
    float4 rs = *reinterpret_cast<const float4*>(&rstd[c]);
    v.x = (v.x - m.x) * rs.x; v.y = (v.y - m.y) * rs.y;
    v.z = (v.z - m.z) * rs.z; v.w = (v.w - m.w) * rs.w;
    *reinterpret_cast<float4*>(&h[(size_t)node * 256 + c]) = v;
}

// ---------------- cluster pooling (CSR gather, no atomics) ----------------
__global__ __launch_bounds__(256) void k_poolavg(
        const float* __restrict__ y, const int* __restrict__ crowptr,
        const int* __restrict__ cdeg, const int* __restrict__ cnodes,
        float* __restrict__ px) {
    int cl = blockIdx.x;
    int c  = threadIdx.x;
    int start = crowptr[cl];
    int cnt = cdeg[cl];
    float acc = 0.f;
    for (int j = 0; j < cnt; j++) {
        int node = cnodes[start + j];
        acc += y[(size_t)node * 256 + c];
    }
    px[(size_t)cl * 256 + c] = acc / fmaxf((float)cnt, 1.0f);
}

__global__ void k_pooledges(const int* __restrict__ src, const int* __restrict__ dst,
                            const int* __restrict__ bc, unsigned char* __restrict__ bmT, int E) {
    int e = blockIdx.x * 256 + threadIdx.x;
    if (e >= E) return;
    int ps = bc[src[e]];
    int pd = bc[dst[e]];
    bmT[(size_t)pd * NCLUST + ps] = 1;
}

// block per dst cluster; 256 threads sum the 1024-byte bitmap row
__global__ __launch_bounds__(256) void k_pooldeg(
        const unsigned char* __restrict__ bmT, float* __restrict__ dinvp) {
    int d = blockIdx.x;
    int t = threadIdx.x;
    const unsigned int v = reinterpret_cast<const unsigned int*>(bmT + (size_t)d * NCLUST)[t];
    int s = (v & 0xff) + ((v >> 8) & 0xff) + ((v >> 16) & 0xff) + ((v >> 24) & 0xff);
    if (t == (d >> 2)) s -= (v >> ((d & 3) * 8)) & 0xff;   // exclude self-loop
    __shared__ int red[256];
    red[t] = s; __syncthreads();
    for (int o = 128; o > 0; o >>= 1) {
        if (t < o) red[t] += red[t + o];
        __syncthreads();
    }
    if (t == 0) dinvp[d] = rsqrtf((float)red[0] + 1.0f);
}

__global__ void k_proppool(const float* __restrict__ h, const float* __restrict__ dinvp,
                           const unsigned char* __restrict__ bmT, const float* __restrict__ bias,
                           float* __restrict__ out, int F) {
    int d = blockIdx.x;
    int f = threadIdx.x;
    float acc = 0.f;
    for (int s = 0; s < NCLUST; s++) {
        if (s == d) continue;
        if (bmT[(size_t)d * NCLUST + s]) acc += dinvp[s] * h[(size_t)s * F + f];
    }
    float di = dinvp[d];
    float r = di * acc + di * di * h[(size_t)d * F + f] + bias[f];
    out[(size_t)d * F + f] = elu1(r);
}

// ---------------------------------------------------------------------------
extern "C" void kernel_launch(void* const* d_in, const int* in_sizes, int n_in,
                              void* d_out, int out_size, void* d_ws, size_t ws_size,
                              hipStream_t stream) {
    const float* x       = (const float*)d_in[0];
    const int*   adj     = (const int*)d_in[1];
    const int*   inb     = (const int*)d_in[3];
    const int*   cluster = (const int*)d_in[4];
    const float* WG1  = (const float*)d_in[5];   const float* bG1  = (const float*)d_in[6];
    const float* WfG1 = (const float*)d_in[7];   const float* bfG1 = (const float*)d_in[8];
    const float* WG2  = (const float*)d_in[9];   const float* bG2  = (const float*)d_in[10];
    const float* WfG2 = (const float*)d_in[11];  const float* bfG2 = (const float*)d_in[12];
    const float* WL1  = (const float*)d_in[13];  const float* bL1  = (const float*)d_in[14];
    const float* WfL1 = (const float*)d_in[15];  const float* bfL1 = (const float*)d_in[16];
    const float* WL2  = (const float*)d_in[17];  const float* bL2  = (const float*)d_in[18];
    const float* WfL2 = (const float*)d_in[19];  const float* bfL2 = (const float*)d_in[20];
    const float* WO1  = (const float*)d_in[21];  const float* bO1  = (const float*)d_in[22];
    const float* WfO1 = (const float*)d_in[23];  const float* bfO1 = (const float*)d_in[24];
    const float* WO2  = (const float*)d_in[25];  const float* bO2  = (const float*)d_in[26];
    const float* WfO2 = (const float*)d_in[27];  const float* bfO2 = (const float*)d_in[28];
    const float* WO3  = (const float*)d_in[29];  const float* bO3  = (const float*)d_in[30];
    const float* WfO3 = (const float*)d_in[31];  const float* bfO3 = (const float*)d_in[32];
    float* out = (float*)d_out;

    const int n = in_sizes[0] / 3;       // 100000
    const int E = in_sizes[1] / 2;       // 1600000
    const int* src = adj;
    const int* dst = adj + E;

    // ---- workspace carve (~173 MB) ----
    char* ws = (char*)d_ws;
    size_t off = 0;
    auto alloc = [&](size_t bytes) -> void* {
        void* p = ws + off;
        off = (off + bytes + 255) & ~(size_t)255;
        return p;
    };
    int*   deg     = (int*)alloc((size_t)n * 4);     // zero span 1 start
    int*   fill    = (int*)alloc((size_t)n * 4);
    int*   cdeg    = (int*)alloc(NCLUST * 4);
    int*   cfill   = (int*)alloc(NCLUST * 4);
    int*   rowptr  = (int*)alloc((size_t)n * 4);     // zero span 1 end (exclusive)
    int*   crowptr = (int*)alloc(NCLUST * 4);
    int*   cnodes  = (int*)alloc((size_t)n * 4);
    int*   bcarr   = (int*)alloc((size_t)n * 4);
    float* dinv    = (float*)alloc((size_t)n * 4);
    int*   bsum    = (int*)alloc(512);
    int*   csr_src = (int*)alloc((size_t)E * 4);
    float* csr_w   = (float*)alloc((size_t)E * 4);
    float* X       = (float*)alloc((size_t)n * 256 * 4);
    float* B       = (float*)alloc((size_t)n * 128 * 4);
    float* insum   = (float*)alloc(256 * 4);         // zero span 2 start
    float* insumsq = (float*)alloc(256 * 4);
    float* px      = (float*)alloc((size_t)NCLUST * 256 * 4);
    unsigned char* bmT = (unsigned char*)alloc((size_t)NCLUST * NCLUST);
    float* mu      = (float*)alloc(256 * 4);         // zero span 2 end (exclusive)
    float* rstd    = (float*)alloc(256 * 4);
    float* dinvp   = (float*)alloc(NCLUST * 4);
    float* lA      = (float*)alloc((size_t)NCLUST * 128 * 4);
    float* lB      = (float*)alloc((size_t)NCLUST * 128 * 4);
    (void)ws_size; (void)n_in; (void)out_size;

    float* B0 = B;
    float* B1 = B + (size_t)n * 64;

    auto cdiv = [](int a, int b) { return (a + b - 1) / b; };
    const int EB = cdiv(E, 256);

    // ---- zero scratch ----
    int nz1 = (int)(((char*)rowptr - (char*)deg) / 16);
    int nz2 = (int)(((char*)mu - (char*)insum) / 16);
    k_zero<<<cdiv(nz1, 256), 256, 0, stream>>>((int4*)deg, nz1);
    k_zero<<<cdiv(nz2, 256), 256, 0, stream>>>((int4*)insum, nz2);

    // ---- CSR build (edges) ----
    k_hist<<<EB, 256, 0, stream>>>(dst, deg, E);
    int nb = cdiv(n, 1024);
    k_scan_block<<<nb, 256, 0, stream>>>(deg, rowptr, bsum, n);
    k_scan_tops<<<1, 128, 0, stream>>>(bsum, nb);
    k_scan_add<<<cdiv(n, 256), 256, 0, stream>>>(rowptr, bsum, n);
    k_dinv_bc<<<cdiv(n, 256), 256, 0, stream>>>(deg, cluster, inb, dinv, bcarr, n);
    k_fill<<<EB, 256, 0, stream>>>(src, dst, dinv, rowptr, fill, csr_src, csr_w, E);

    // ---- CSR build (cluster member lists) ----
    k_hist<<<cdiv(n, 256), 256, 0, stream>>>(bcarr, cdeg, n);
    k_scan_block<<<1, 256, 0, stream>>>(cdeg, crowptr, bsum, NCLUST);
    k_cfill<<<cdiv(n, 256), 256, 0, stream>>>(bcarr, crowptr, cfill, cnodes, n);

    // ---- global GCN stack ----
    k_prop3<<<cdiv(n, 256), 256, 0, stream>>>(x, dinv, rowptr, deg, csr_src, csr_w,
                                              nullptr, B0, n, 0);
    k_fc<64, 2><<<cdiv(n, 32), 256, 0, stream>>>(B0, WG1, bG1, nullptr, nullptr, B1, n, 3, 1);
    // h2 = elu(h1 @ WfG1 + bfG1)  (B1 in-place, 64 square)
    k_gemm<64, 64, 16, 4><<<cdiv(n, 64), 256, 0, stream>>>(B1, WfG1, bfG1, nullptr, nullptr,
                                                           B1, n, 64, 1);
    k_prop4<<<cdiv(n * 16, 256), 256, 0, stream>>>(B1, dinv, rowptr, deg, csr_src, csr_w,
                                                   nullptr, B0, n, 64, 4, 0);
    // h3 = elu(p64 @ WG2 + bG2)  (X)
    k_gemm<64, 256, 16, 2><<<cdiv(n, 64), 256, 0, stream>>>(B0, WG2, bG2, nullptr, nullptr,
                                                            X, n, 64, 1);
    // h4 = elu(h3 @ WfG2 + bfG2)  (X in-place)
    k_gemm<64, 256, 16, 2><<<cdiv(n, 64), 256, 0, stream>>>(X, WfG2, bfG2, nullptr, nullptr,
                                                            X, n, 256, 1);

    // ---- instance norm (in place) -> y = X ----
    k_instats<<<cdiv(n, 128), 256, 0, stream>>>(X, insum, insumsq, n);
    k_infinal<<<1, 256, 0, stream>>>(insum, insumsq, mu, rstd, n);
    k_innorm<<<cdiv(n * 64, 256), 256, 0, stream>>>(X, mu, rstd, n);

    // ---- cluster pooling (gather) ----
    k_poolavg<<<NCLUST, 256, 0, stream>>>(X, crowptr, cdeg, cnodes, px);
    k_pooledges<<<EB, 256, 0, stream>>>(src, dst, bcarr, bmT, E);
    k_pooldeg<<<NCLUST, 256, 0, stream>>>(bmT, dinvp);

    // ---- local (pooled) GCN stack ----
    k_fc<128, 2><<<cdiv(NCLUST, 16), 256, 0, stream>>>(px, WL1, nullptr, nullptr, nullptr,
                                                       lA, NCLUST, 256, 0);
    k_proppool<<<NCLUST, 128, 0, stream>>>(lA, dinvp, bmT, bL1, lB, 128);
    k_fc<128, 2><<<cdiv(NCLUST, 16), 256, 0, stream>>>(lB, WfL1, bfL1, nullptr, nullptr,
                                                       lA, NCLUST, 128, 1);
    k_fc<64, 2><<<cdiv(NCLUST, 32), 256, 0, stream>>>(lA, WL2, nullptr, nullptr, nullptr,
                                                      lB, NCLUST, 128, 0);
    k_proppool<<<NCLUST, 64, 0, stream>>>(lB, dinvp, bmT, bL2, lA, 64);
    k_fc<64, 2><<<cdiv(NCLUST, 32), 256, 0, stream>>>(lA, WfL2, bfL2, nullptr, nullptr,
                                                      lB, NCLUST, 64, 1);
    k_fc<128, 2><<<cdiv(NCLUST, 16), 256, 0, stream>>>(lB, WO1 + (size_t)256 * 128, nullptr,
                                                       nullptr, nullptr, lA, NCLUST, 64, 0);

    // ---- output GCN stack ----
    // t1 = y @ WO1[0:256,:] + compO[bc]  (B, N x 128)
    k_gemm<64, 128, 16, 2><<<cdiv(n, 64), 256, 0, stream>>>(X, WO1, nullptr, lA, bcarr,
                                                            B, n, 256, 0);
    k_prop4<<<cdiv(n * 32, 256), 256, 0, stream>>>(B, dinv, rowptr, deg, csr_src, csr_w,
                                                   bO1, X, n, 128, 5, 1);
    // o2 = elu(o1 @ WfO1 + bfO1)  (X in-place)
    k_gemm<64, 128, 16, 2><<<cdiv(n, 64), 256, 0, stream>>>(X, WfO1, bfO1, nullptr, nullptr,
                                                            X, n, 128, 1);
    // t2 = o2 @ WO2  (B, N x 32)
    k_gemm<64, 32, 16, 8><<<cdiv(n, 64), 256, 0, stream>>>(X, WO2, nullptr, nullptr, nullptr,
                                                           B, n, 128, 0);
    k_prop4<<<cdiv(n * 8, 256), 256, 0, stream>>>(B, dinv, rowptr, deg, csr_src, csr_w,
                                                  bO2, X, n, 32, 3, 1);
    // o4 = elu(o3 @ WfO2 + bfO2)  (X in-place)
    k_gemm<64, 32, 16, 8><<<cdiv(n, 64), 256, 0, stream>>>(X, WfO2, bfO2, nullptr, nullptr,
                                                           X, n, 32, 1);
    k_fc3<<<cdiv(n, 256), 256, 0, stream>>>(X, WO3, nullptr, B, n, 32, 0);
    k_prop3<<<cdiv(n, 256), 256, 0, stream>>>(B, dinv, rowptr, deg, csr_src, csr_w,
                                              bO3, X, n, 1);
    k_fc3<<<cdiv(n, 256), 256, 0, stream>>>(X, WfO3, bfO3, out, n, 3, 1);
}